// Round 1
// baseline (113.327 us; speedup 1.0000x reference)
//
#include <hip/hip_runtime.h>

#define NIN 256
#define G 16
#define U 16
#define F 32
#define LEVELS 4
#define ROWS 16          // rows per block
#define STRIDE 1028      // LDS row stride in floats (16B-aligned rows)

__device__ __forceinline__ float fast_tanh(float x) {
    // tanh(x) = 1 - 2/(exp(2x)+1); exp(2x) = exp2(x * 2*log2(e))
    float e = __builtin_amdgcn_exp2f(x * 2.8853900817779268f);
    return 1.0f - 2.0f * __builtin_amdgcn_rcpf(e + 1.0f);
}

extern "C" __global__ __launch_bounds__(256, 2)
void denc_kernel(const float* __restrict__ x,
                 const float* __restrict__ k1, const float* __restrict__ b1, const int* __restrict__ i1,
                 const float* __restrict__ k2, const float* __restrict__ b2, const int* __restrict__ i2,
                 const float* __restrict__ k3, const float* __restrict__ b3, const int* __restrict__ i3,
                 const float* __restrict__ k4, const float* __restrict__ b4, const int* __restrict__ i4,
                 float* __restrict__ out)
{
    __shared__ float flat[ROWS][STRIDE];

    const int tid  = threadIdx.x;
    const int wave = tid >> 6;        // 0..3, owns rows 4w..4w+3
    const int lane = tid & 63;
    const int g    = lane >> 2;       // 0..15
    const int qq   = lane & 3;        // u-quad 0..3
    const int r0   = blockIdx.x * ROWS;

    // ---- stage x tile (wave-local rows => no barrier needed anywhere) ----
    {
        const float4* xg = reinterpret_cast<const float4*>(x + (size_t)r0 * NIN);
        #pragma unroll
        for (int i = 0; i < 4; ++i) {
            int v   = wave * 256 + i * 64 + lane;   // float4 index in 16x256 tile
            int row = v >> 6;                        // = wave*4 + i
            int c4  = v & 63;
            float4 val = xg[v];
            *reinterpret_cast<float4*>(&flat[row][c4 * 4]) = val;
        }
    }
    // No __syncthreads(): each wave stages exactly the rows it computes.

    const float* Ks[LEVELS] = {k1, k2, k3, k4};
    const float* Bs[LEVELS] = {b1, b2, b3, b4};
    const int*   Is[LEVELS] = {i1, i2, i3, i4};

    #pragma unroll
    for (int l = 0; l < LEVELS; ++l) {
        const float* Kp = Ks[l];
        const float* Bp = Bs[l];
        const int*   Ip = Is[l];

        // per-thread K slice: kq[f] = K[g][f][4qq .. 4qq+3]  (128 VGPRs)
        float4 kq[F];
        #pragma unroll
        for (int f = 0; f < F; ++f)
            kq[f] = reinterpret_cast<const float4*>(Kp)[(g * F + f) * 4 + qq];

        int ioff[F];
        #pragma unroll
        for (int f = 0; f < F; ++f)
            ioff[f] = Ip[g * F + f];

        const float4 bv = reinterpret_cast<const float4*>(Bp)[g * 4 + qq];
        const int obase = NIN + l * (G * U);

        #pragma unroll
        for (int rr = 0; rr < 4; ++rr) {
            const int row = wave * 4 + rr;
            const float* fr = flat[row];
            float a0 = bv.x, a1 = bv.y, a2 = bv.z, a3 = bv.w;
            #pragma unroll
            for (int f = 0; f < F; ++f) {
                float s = fr[ioff[f]];
                a0 = fmaf(s, kq[f].x, a0);
                a1 = fmaf(s, kq[f].y, a1);
                a2 = fmaf(s, kq[f].z, a2);
                a3 = fmaf(s, kq[f].w, a3);
            }
            a0 = fast_tanh(a0);
            a1 = fast_tanh(a1);
            a2 = fast_tanh(a2);
            a3 = fast_tanh(a3);
            if (l < LEVELS - 1) {
                *reinterpret_cast<float4*>(&flat[row][obase + g * U + qq * 4]) =
                    make_float4(a0, a1, a2, a3);
            } else {
                *reinterpret_cast<float4*>(out + (size_t)(r0 + row) * (G * U) + g * U + qq * 4) =
                    make_float4(a0, a1, a2, a3);
            }
        }
        // No barrier: writes target cols >= obase (own rows only); this
        // level's gathers only read cols < obase, next level reads are
        // same-wave dependent => in-order per wave.
    }
}

extern "C" void kernel_launch(void* const* d_in, const int* in_sizes, int n_in,
                              void* d_out, int out_size, void* d_ws, size_t ws_size,
                              hipStream_t stream) {
    const float* x  = (const float*)d_in[0];
    const float* k1 = (const float*)d_in[1];
    const float* b1 = (const float*)d_in[2];
    const int*   i1 = (const int*)  d_in[3];
    const float* k2 = (const float*)d_in[4];
    const float* b2 = (const float*)d_in[5];
    const int*   i2 = (const int*)  d_in[6];
    const float* k3 = (const float*)d_in[7];
    const float* b3 = (const float*)d_in[8];
    const int*   i3 = (const int*)  d_in[9];
    const float* k4 = (const float*)d_in[10];
    const float* b4 = (const float*)d_in[11];
    const int*   i4 = (const int*)  d_in[12];
    float* out = (float*)d_out;

    const int batch = in_sizes[0] / NIN;      // 65536
    dim3 grid(batch / ROWS);                  // 4096 blocks
    dim3 block(256);
    hipLaunchKernelGGL(denc_kernel, grid, block, 0, stream,
                       x, k1, b1, i1, k2, b2, i2, k3, b3, i3, k4, b4, i4, out);
}